// Round 4
// baseline (1125.302 us; speedup 1.0000x reference)
//
#include <hip/hip_runtime.h>
#include <hip/hip_bf16.h>

typedef _Float16 f16x4 __attribute__((ext_vector_type(4)));
typedef float f32x16 __attribute__((ext_vector_type(16)));

#define SCALE_Q 0.17677669529663687f

// ---------- ws layout (bytes) ----------
#define WQKVP_OFF  0ull        // f16 [9][12][64][4]  = 55296 B
#define WPP_OFF    55296ull    // f16 [3][12][64][4]  = 18432 B
#define W1P_OFF    73728ull    // f16 [12][12][64][4] = 73728 B
#define W2P_OFF    147456ull   // f16 [3][48][64][4]  = 73728 B
#define BIASBT_OFF 221184ull   // f32 [3][98][98]     = 115248 B

// ---------------- prep: pack B-fragments in MFMA lane order + transposed bias ----------------
__global__ __launch_bounds__(256) void k_prep(
    const float* __restrict__ w_qkv, const float* __restrict__ w_proj,
    const float* __restrict__ w_fc1, const float* __restrict__ w_fc2,
    const float* __restrict__ btab, const int* __restrict__ relidx,
    char* __restrict__ ws) {
    _Float16* wqkvp = (_Float16*)(ws + WQKVP_OFF);
    _Float16* wpp   = (_Float16*)(ws + WPP_OFF);
    _Float16* w1p   = (_Float16*)(ws + W1P_OFF);
    _Float16* w2p   = (_Float16*)(ws + W2P_OFF);
    float*    biasbT = (float*)(ws + BIASBT_OFF);
    int e = blockIdx.x * 256 + threadIdx.x;
    if (e < 27648) {                       // wqkvp: 9 ct x 12 S x 64 l x 4
        int ct = e / 3072; int r = e % 3072;
        int S = r >> 8; int li = (r >> 2) & 63; int j4 = r & 3;
        int k = 8 * S + 4 * (li >> 5) + j4, col = ct * 32 + (li & 31);
        wqkvp[e] = (_Float16)w_qkv[k * 288 + col];
    } else if (e < 36864) {                // wpp: 3 x 12 x 256
        int r0 = e - 27648;
        int ct = r0 / 3072; int r = r0 % 3072;
        int S = r >> 8; int li = (r >> 2) & 63; int j4 = r & 3;
        int k = 8 * S + 4 * (li >> 5) + j4, col = ct * 32 + (li & 31);
        wpp[r0] = (_Float16)w_proj[k * 96 + col];
    } else if (e < 73728) {                // w1p: 12 x 12 x 256
        int r0 = e - 36864;
        int ct = r0 / 3072; int r = r0 % 3072;
        int S = r >> 8; int li = (r >> 2) & 63; int j4 = r & 3;
        int k = 8 * S + 4 * (li >> 5) + j4, col = ct * 32 + (li & 31);
        w1p[r0] = (_Float16)w_fc1[k * 384 + col];
    } else if (e < 110592) {               // w2p: 3 ct x 48 S x 256
        int r0 = e - 73728;
        int ct = r0 / 12288; int r = r0 % 12288;
        int S = r >> 8; int li = (r >> 2) & 63; int j4 = r & 3;
        int k = 8 * S + 4 * (li >> 5) + j4, col = ct * 32 + (li & 31);
        w2p[r0] = (_Float16)w_fc2[k * 96 + col];
    } else if (e < 110592 + 28812) {       // biasbT[h][j][i]
        int r = e - 110592; int hh = r / 9604; int ji = r % 9604;
        int j = ji / 98, i = ji % 98;
        biasbT[r] = btab[relidx[i * 98 + j] * 3 + hh];
    }
}

// ---------------- fused: LN1+shift+QKV+attn+PV+proj+residual, one block per window ----------------
// LDS: xw f16[128][100] @0 | Qs f16[128][36] @25600 | Ks f16[128][36] @34816
//      VTs f16[32][140] @44032 | labL u8[128] @52992 ; stage f32[98][97] aliases @0
__global__ __launch_bounds__(256, 3) void k_attn4(
    const float* __restrict__ x,
    const float* __restrict__ g1v, const float* __restrict__ b1v,
    const float* __restrict__ b_qkv, const float* __restrict__ b_proj,
    const char* __restrict__ ws,
    float* __restrict__ out) {
    __shared__ __align__(16) char smem[53120];
    _Float16* xw   = (_Float16*)smem;              // [128][100]
    _Float16* Qs   = (_Float16*)(smem + 25600);    // [128][36]
    _Float16* Ks   = (_Float16*)(smem + 34816);    // [128][36]
    _Float16* VTs  = (_Float16*)(smem + 44032);    // [32][140]
    float*    stage = (float*)smem;                // [98][97]
    unsigned char* labL = (unsigned char*)(smem + 52992);

    const _Float16* wqkvp = (const _Float16*)(ws + WQKVP_OFF);
    const _Float16* wpp   = (const _Float16*)(ws + WPP_OFF);
    const float* biasbT   = (const float*)(ws + BIASBT_OFF);

    const int tid = threadIdx.x;
    const int w = blockIdx.x;
    const int b = w >> 9, nwi = w & 511;
    const int dq = nwi >> 6, hq = (nwi >> 3) & 7, wq = nwi & 7;

    // region labels for the shifted-window mask
    if (tid < 128) {
        int t = tid;
        unsigned char lv = 255;
        if (t < 98) {
            int td = t / 49; int r = t - td * 49; int th = r / 7; int tw = r - th * 7;
            int d0 = dq * 2 + td, h0 = hq * 7 + th, w0 = wq * 7 + tw;
            int ld = (d0 < 14) ? 0 : ((d0 < 15) ? 1 : 2);
            int lh = (h0 < 49) ? 0 : ((h0 < 53) ? 1 : 2);
            int lw = (w0 < 49) ? 0 : ((w0 < 53) ? 1 : 2);
            lv = (unsigned char)((ld * 3 + lh) * 3 + lw);
        }
        labL[t] = lv;
    }
    // zero xw tail rows 98..127 and VTs tail cols 98..139
    for (int e = tid; e < 3000; e += 256) xw[9800 + e] = (_Float16)0.f;
    for (int e = tid; e < 1344; e += 256) {
        int rr = e / 42, cc = 98 + (e - rr * 42);
        VTs[rr * 140 + cc] = (_Float16)0.f;
    }
    // LN1 + cyclic shift gather -> xw
    {
        const int lane = tid & 31, sub = tid >> 5;
        for (int it = 0; it < 13; ++it) {
            int t = sub + 8 * it;
            if (t < 98) {
                int td = t / 49; int r = t - td * 49; int th = r / 7; int tw = r - th * 7;
                int gd = (dq * 2 + td + 1) & 15;
                int gh = hq * 7 + th + 3; if (gh >= 56) gh -= 56;
                int gw = wq * 7 + tw + 3; if (gw >= 56) gw -= 56;
                const float* row = x + (size_t)(((b * 16 + gd) * 56 + gh) * 56 + gw) * 96;
                float v0 = row[lane], v1 = row[lane + 32], v2 = row[lane + 64];
                float s = v0 + v1 + v2, s2 = v0 * v0 + v1 * v1 + v2 * v2;
                #pragma unroll
                for (int off = 16; off >= 1; off >>= 1) {
                    s  += __shfl_xor(s,  off, 32);
                    s2 += __shfl_xor(s2, off, 32);
                }
                float mu = s * (1.f / 96.f);
                float rs = rsqrtf(s2 * (1.f / 96.f) - mu * mu + 1e-5f);
                xw[t * 100 + lane]      = (_Float16)((v0 - mu) * rs * g1v[lane]      + b1v[lane]);
                xw[t * 100 + lane + 32] = (_Float16)((v1 - mu) * rs * g1v[lane + 32] + b1v[lane + 32]);
                xw[t * 100 + lane + 64] = (_Float16)((v2 - mu) * rs * g1v[lane + 64] + b1v[lane + 64]);
            }
        }
    }
    __syncthreads();

    const int l = tid & 63, wid = tid >> 6, n = l & 31, hi = l >> 5;
    const int mtb = wid * 32;          // this wave's token/query tile base

    // A-fragments of xw (rows mtb..mtb+31), reused for all heads/sels
    f16x4 af[12];
    #pragma unroll
    for (int ks = 0; ks < 12; ++ks)
        af[ks] = *(const f16x4*)&xw[(mtb + n) * 100 + 8 * ks + 4 * hi];

    f16x4 ofr[3][4];                   // per-head O^T B-fragments (k = h*32+hd)

    for (int h = 0; h < 3; ++h) {
        // ---- QKV (D[m=t][n=hd]) ----
        #pragma unroll
        for (int sel = 0; sel < 3; ++sel) {
            int ct = sel * 3 + h;
            float bias = b_qkv[sel * 96 + h * 32 + n];
            f32x16 acc;
            #pragma unroll
            for (int r2 = 0; r2 < 16; ++r2) acc[r2] = bias;
            #pragma unroll
            for (int ks = 0; ks < 12; ++ks) {
                f16x4 bf = *(const f16x4*)&wqkvp[((ct * 12 + ks) * 64 + l) * 4];
                acc = __builtin_amdgcn_mfma_f32_32x32x8f16(af[ks], bf, acc, 0, 0, 0);
            }
            #pragma unroll
            for (int rg = 0; rg < 16; ++rg) {
                int t = mtb + (rg & 3) + 8 * (rg >> 2) + 4 * hi;
                float v = acc[rg];
                if (sel == 0)      Qs[t * 36 + n] = (_Float16)(v * SCALE_Q);
                else if (sel == 1) Ks[t * 36 + n] = (_Float16)v;
                else if (t < 98)   VTs[n * 140 + t] = (_Float16)v;
            }
        }
        __syncthreads();

        // ---- S^T = K @ Q^T  (D[m=j][n=i], lane owns query i = mtb+n) ----
        f32x16 sc[4];
        #pragma unroll
        for (int jt = 0; jt < 4; ++jt) {
            f32x16 a;
            #pragma unroll
            for (int r2 = 0; r2 < 16; ++r2) a[r2] = 0.f;
            #pragma unroll
            for (int ks = 0; ks < 4; ++ks) {
                f16x4 ak = *(const f16x4*)&Ks[(jt * 32 + n) * 36 + 8 * ks + 4 * hi];
                f16x4 bq = *(const f16x4*)&Qs[(mtb + n) * 36 + 8 * ks + 4 * hi];
                a = __builtin_amdgcn_mfma_f32_32x32x8f16(ak, bq, a, 0, 0, 0);
            }
            sc[jt] = a;
        }
        // bias + mask + in-lane softmax
        {
            const int i = mtb + n;
            const bool iv = (i < 98);
            const unsigned char li = labL[i];
            const float* bb = biasbT + (size_t)h * 9604;
            float m = -1e30f;
            #pragma unroll
            for (int jt = 0; jt < 4; ++jt) {
                #pragma unroll
                for (int rg = 0; rg < 16; ++rg) {
                    int j = jt * 32 + (rg & 3) + 8 * (rg >> 2) + 4 * hi;
                    float s;
                    if (j < 98 && iv)
                        s = sc[jt][rg] + bb[j * 98 + i] + ((li != labL[j]) ? -100.f : 0.f);
                    else
                        s = -1e30f;
                    sc[jt][rg] = s;
                    m = fmaxf(m, s);
                }
            }
            m = fmaxf(m, __shfl_xor(m, 32));
            float ssum = 0.f;
            #pragma unroll
            for (int jt = 0; jt < 4; ++jt)
                #pragma unroll
                for (int rg = 0; rg < 16; ++rg) {
                    float p = __expf(sc[jt][rg] - m);
                    sc[jt][rg] = p;
                    ssum += p;
                }
            ssum += __shfl_xor(ssum, 32);
            float inv = 1.f / ssum;
            #pragma unroll
            for (int jt = 0; jt < 4; ++jt)
                #pragma unroll
                for (int rg = 0; rg < 16; ++rg) sc[jt][rg] *= inv;
        }
        // ---- PV: O^T[hd][t] ; B = P^T straight from sc registers ----
        {
            f32x16 oacc;
            #pragma unroll
            for (int r2 = 0; r2 < 16; ++r2) oacc[r2] = 0.f;
            #pragma unroll
            for (int jt = 0; jt < 4; ++jt) {
                #pragma unroll
                for (int s4 = 0; s4 < 4; ++s4) {
                    f16x4 pf;
                    pf[0] = (_Float16)sc[jt][4 * s4 + 0];
                    pf[1] = (_Float16)sc[jt][4 * s4 + 1];
                    pf[2] = (_Float16)sc[jt][4 * s4 + 2];
                    pf[3] = (_Float16)sc[jt][4 * s4 + 3];
                    f16x4 av = *(const f16x4*)&VTs[n * 140 + 8 * (jt * 4 + s4) + 4 * hi];
                    oacc = __builtin_amdgcn_mfma_f32_32x32x8f16(av, pf, oacc, 0, 0, 0);
                }
            }
            #pragma unroll
            for (int s4 = 0; s4 < 4; ++s4) {
                f16x4 q;
                q[0] = (_Float16)oacc[4 * s4 + 0];
                q[1] = (_Float16)oacc[4 * s4 + 1];
                q[2] = (_Float16)oacc[4 * s4 + 2];
                q[3] = (_Float16)oacc[4 * s4 + 3];
                ofr[h][s4] = q;
            }
        }
        __syncthreads();   // before next head's QKV overwrites Qs/Ks/VTs (also guards stage alias)
    }

    // ---- proj: OUT^T[col][t] ; B = O^T from registers, A = packed Wp^T ----
    #pragma unroll
    for (int ct = 0; ct < 3; ++ct) {
        f32x16 acc;
        #pragma unroll
        for (int r2 = 0; r2 < 16; ++r2) acc[r2] = 0.f;
        #pragma unroll
        for (int S = 0; S < 12; ++S) {
            f16x4 aw = *(const f16x4*)&wpp[((ct * 12 + S) * 64 + l) * 4];
            acc = __builtin_amdgcn_mfma_f32_32x32x8f16(aw, ofr[S >> 2][S & 3], acc, 0, 0, 0);
        }
        int t = mtb + n;
        if (t < 98) {
            #pragma unroll
            for (int rg = 0; rg < 16; ++rg) {
                int col = ct * 32 + (rg & 3) + 8 * (rg >> 2) + 4 * hi;
                stage[t * 97 + col] = acc[rg];
            }
        }
    }
    __syncthreads();
    // ---- out = x + stage + b_proj (coalesced) ----
    for (int e = tid; e < 2352; e += 256) {
        int t = e / 24, q4 = (e - (e / 24) * 24) * 4;
        int td = t / 49; int r = t - td * 49; int th = r / 7; int tw = r - th * 7;
        int gd = (dq * 2 + td + 1) & 15;
        int gh = hq * 7 + th + 3; if (gh >= 56) gh -= 56;
        int gw = wq * 7 + tw + 3; if (gw >= 56) gw -= 56;
        size_t base = (size_t)(((b * 16 + gd) * 56 + gh) * 56 + gw) * 96 + q4;
        float4 xv = *(const float4*)&x[base];
        float4 bp = *(const float4*)&b_proj[q4];
        out[base + 0] = xv.x + bp.x + stage[t * 97 + q4 + 0];
        out[base + 1] = xv.y + bp.y + stage[t * 97 + q4 + 1];
        out[base + 2] = xv.z + bp.z + stage[t * 97 + q4 + 2];
        out[base + 3] = xv.w + bp.w + stage[t * 97 + q4 + 3];
    }
}

// ---------------- MLP: LN2 + FC1 + GELU + FC2 + residual, 64 tokens/block ----------------
__global__ __launch_bounds__(256, 2) void k_mlp4(
    const float* __restrict__ g2v, const float* __restrict__ b2v,
    const float* __restrict__ b_fc1, const float* __restrict__ b_fc2,
    const char* __restrict__ ws,
    float* __restrict__ out) {
    __shared__ _Float16 xb[64 * 100];
    __shared__ _Float16 hb[64 * 388];
    const _Float16* w1p = (const _Float16*)(ws + W1P_OFF);
    const _Float16* w2p = (const _Float16*)(ws + W2P_OFF);
    const int tid = threadIdx.x;
    const size_t tokBase = (size_t)blockIdx.x * 64;
    {
        const int lane = tid & 31, sub = tid >> 5;
        for (int it = 0; it < 8; ++it) {
            int rt = sub + 8 * it;
            const float* row = out + (tokBase + rt) * 96;
            float v0 = row[lane], v1 = row[lane + 32], v2 = row[lane + 64];
            float s = v0 + v1 + v2, s2 = v0 * v0 + v1 * v1 + v2 * v2;
            #pragma unroll
            for (int off = 16; off >= 1; off >>= 1) {
                s  += __shfl_xor(s,  off, 32);
                s2 += __shfl_xor(s2, off, 32);
            }
            float mu = s * (1.f / 96.f);
            float rs = rsqrtf(s2 * (1.f / 96.f) - mu * mu + 1e-5f);
            xb[rt * 100 + lane]      = (_Float16)((v0 - mu) * rs * g2v[lane]      + b2v[lane]);
            xb[rt * 100 + lane + 32] = (_Float16)((v1 - mu) * rs * g2v[lane + 32] + b2v[lane + 32]);
            xb[rt * 100 + lane + 64] = (_Float16)((v2 - mu) * rs * g2v[lane + 64] + b2v[lane + 64]);
        }
    }
    __syncthreads();
    const int l = tid & 63, wid = tid >> 6, n = l & 31, hi = l >> 5;
    // FC1 + GELU -> hb
    {
        const int mt = wid & 1;
        const int nt0 = wid >> 1;
        f16x4 af[12];
        #pragma unroll
        for (int ks = 0; ks < 12; ++ks)
            af[ks] = *(const f16x4*)&xb[(mt * 32 + n) * 100 + 8 * ks + 4 * hi];
        for (int s6 = 0; s6 < 6; ++s6) {
            int nt = nt0 + 2 * s6;
            float bias = b_fc1[nt * 32 + n];
            f32x16 acc;
            #pragma unroll
            for (int r2 = 0; r2 < 16; ++r2) acc[r2] = bias;
            #pragma unroll
            for (int ks = 0; ks < 12; ++ks) {
                f16x4 bf = *(const f16x4*)&w1p[((nt * 12 + ks) * 64 + l) * 4];
                acc = __builtin_amdgcn_mfma_f32_32x32x8f16(af[ks], bf, acc, 0, 0, 0);
            }
            #pragma unroll
            for (int rg = 0; rg < 16; ++rg) {
                int r2 = mt * 32 + (rg & 3) + 8 * (rg >> 2) + 4 * hi;
                float v = acc[rg];
                hb[r2 * 388 + nt * 32 + n] = (_Float16)(0.5f * v * (1.f + erff(v * 0.70710678118654752f)));
            }
        }
    }
    __syncthreads();
    // FC2 + residual
    for (int u = wid; u < 6; u += 4) {
        int nt = u >> 1, mt = u & 1;
        float bias = b_fc2[nt * 32 + n];
        f32x16 acc;
        #pragma unroll
        for (int r2 = 0; r2 < 16; ++r2) acc[r2] = bias;
        #pragma unroll
        for (int ks = 0; ks < 48; ++ks) {
            f16x4 ah = *(const f16x4*)&hb[(mt * 32 + n) * 388 + 8 * ks + 4 * hi];
            f16x4 bf = *(const f16x4*)&w2p[((nt * 48 + ks) * 64 + l) * 4];
            acc = __builtin_amdgcn_mfma_f32_32x32x8f16(ah, bf, acc, 0, 0, 0);
        }
        #pragma unroll
        for (int rg = 0; rg < 16; ++rg) {
            int t = mt * 32 + (rg & 3) + 8 * (rg >> 2) + 4 * hi;
            size_t idx = (tokBase + t) * 96 + nt * 32 + n;
            out[idx] = out[idx] + acc[rg];
        }
    }
}

extern "C" void kernel_launch(void* const* d_in, const int* in_sizes, int n_in,
                              void* d_out, int out_size, void* d_ws, size_t ws_size,
                              hipStream_t stream) {
    const float* x      = (const float*)d_in[0];
    const float* g1     = (const float*)d_in[2];
    const float* b1     = (const float*)d_in[3];
    const float* w_qkv  = (const float*)d_in[4];
    const float* b_qkv  = (const float*)d_in[5];
    const float* w_proj = (const float*)d_in[6];
    const float* b_proj = (const float*)d_in[7];
    const float* btab   = (const float*)d_in[8];
    const int*   relidx = (const int*)d_in[9];
    const float* g2     = (const float*)d_in[10];
    const float* b2     = (const float*)d_in[11];
    const float* w_fc1  = (const float*)d_in[12];
    const float* b_fc1  = (const float*)d_in[13];
    const float* w_fc2  = (const float*)d_in[14];
    const float* b_fc2  = (const float*)d_in[15];
    float* out = (float*)d_out;
    char*  ws  = (char*)d_ws;

    hipLaunchKernelGGL(k_prep, dim3(545), dim3(256), 0, stream,
                       w_qkv, w_proj, w_fc1, w_fc2, btab, relidx, ws);
    hipLaunchKernelGGL(k_attn4, dim3(4096), dim3(256), 0, stream,
                       x, g1, b1, b_qkv, b_proj, (const char*)ws, out);
    hipLaunchKernelGGL(k_mlp4, dim3(401408 / 64), dim3(256), 0, stream,
                       g2, b2, b_fc1, b_fc2, (const char*)ws, out);
}

// Round 5
// 755.327 us; speedup vs baseline: 1.4898x; 1.4898x over previous
//
#include <hip/hip_runtime.h>
#include <hip/hip_bf16.h>

typedef _Float16 f16x4 __attribute__((ext_vector_type(4)));
typedef float f32x16 __attribute__((ext_vector_type(16)));

#define SCALE_Q 0.17677669529663687f

// ---------- ws layout (bytes) ----------
#define WQKVP_OFF  0ull        // f16 [9][12][64][4]  = 55296 B
#define WPP_OFF    55296ull    // f16 [3][12][64][4]  = 18432 B
#define W1P_OFF    73728ull    // f16 [12][12][64][4] = 73728 B
#define W2P_OFF    147456ull   // f16 [3][48][64][4]  = 73728 B
#define BIASBT_OFF 221184ull   // f32 [3][98][98]     = 115248 B

// ---------------- prep: pack B-fragments in MFMA lane order + transposed bias ----------------
__global__ __launch_bounds__(256) void k_prep(
    const float* __restrict__ w_qkv, const float* __restrict__ w_proj,
    const float* __restrict__ w_fc1, const float* __restrict__ w_fc2,
    const float* __restrict__ btab, const int* __restrict__ relidx,
    char* __restrict__ ws) {
    _Float16* wqkvp = (_Float16*)(ws + WQKVP_OFF);
    _Float16* wpp   = (_Float16*)(ws + WPP_OFF);
    _Float16* w1p   = (_Float16*)(ws + W1P_OFF);
    _Float16* w2p   = (_Float16*)(ws + W2P_OFF);
    float*    biasbT = (float*)(ws + BIASBT_OFF);
    int e = blockIdx.x * 256 + threadIdx.x;
    if (e < 27648) {                       // wqkvp: 9 ct x 12 S x 64 l x 4
        int ct = e / 3072; int r = e % 3072;
        int S = r >> 8; int li = (r >> 2) & 63; int j4 = r & 3;
        int k = 8 * S + 4 * (li >> 5) + j4, col = ct * 32 + (li & 31);
        wqkvp[e] = (_Float16)w_qkv[k * 288 + col];
    } else if (e < 36864) {                // wpp: 3 x 12 x 256
        int r0 = e - 27648;
        int ct = r0 / 3072; int r = r0 % 3072;
        int S = r >> 8; int li = (r >> 2) & 63; int j4 = r & 3;
        int k = 8 * S + 4 * (li >> 5) + j4, col = ct * 32 + (li & 31);
        wpp[r0] = (_Float16)w_proj[k * 96 + col];
    } else if (e < 73728) {                // w1p: 12 x 12 x 256
        int r0 = e - 36864;
        int ct = r0 / 3072; int r = r0 % 3072;
        int S = r >> 8; int li = (r >> 2) & 63; int j4 = r & 3;
        int k = 8 * S + 4 * (li >> 5) + j4, col = ct * 32 + (li & 31);
        w1p[r0] = (_Float16)w_fc1[k * 384 + col];
    } else if (e < 110592) {               // w2p: 3 ct x 48 S x 256
        int r0 = e - 73728;
        int ct = r0 / 12288; int r = r0 % 12288;
        int S = r >> 8; int li = (r >> 2) & 63; int j4 = r & 3;
        int k = 8 * S + 4 * (li >> 5) + j4, col = ct * 32 + (li & 31);
        w2p[r0] = (_Float16)w_fc2[k * 96 + col];
    } else if (e < 110592 + 28812) {       // biasbT[h][j][i]
        int r = e - 110592; int hh = r / 9604; int ji = r % 9604;
        int j = ji / 98, i = ji % 98;
        biasbT[r] = btab[relidx[i * 98 + j] * 3 + hh];
    }
}

// ---------------- fused: LN1+shift+QKV+attn+PV+proj+residual, one block per window ----------------
// LDS: xw f16[128][100] @0 | Qs f16[128][36] @25600 | Ks f16[128][36] @34816
//      VTs f16[32][140] @44032 | labL u8[128] @52992 ; stage f32[98][97] aliases @0
__global__ __launch_bounds__(256, 3) void k_attn5(
    const float* __restrict__ x,
    const float* __restrict__ g1v, const float* __restrict__ b1v,
    const float* __restrict__ b_qkv, const float* __restrict__ b_proj,
    const char* __restrict__ ws,
    float* __restrict__ out) {
    __shared__ __align__(16) char smem[53120];
    _Float16* xw   = (_Float16*)smem;              // [128][100]
    _Float16* Qs   = (_Float16*)(smem + 25600);    // [128][36]
    _Float16* Ks   = (_Float16*)(smem + 34816);    // [128][36]
    _Float16* VTs  = (_Float16*)(smem + 44032);    // [32][140]
    float*    stage = (float*)smem;                // [98][97]
    unsigned char* labL = (unsigned char*)(smem + 52992);

    const _Float16* wqkvp = (const _Float16*)(ws + WQKVP_OFF);
    const _Float16* wpp   = (const _Float16*)(ws + WPP_OFF);
    const float* biasbT   = (const float*)(ws + BIASBT_OFF);

    const int tid = threadIdx.x;
    const int w = blockIdx.x;
    const int b = w >> 9, nwi = w & 511;
    const int dq = nwi >> 6, hq = (nwi >> 3) & 7, wq = nwi & 7;

    // region labels for the shifted-window mask
    if (tid < 128) {
        int t = tid;
        unsigned char lv = 255;
        if (t < 98) {
            int td = t / 49; int r = t - td * 49; int th = r / 7; int tw = r - th * 7;
            int d0 = dq * 2 + td, h0 = hq * 7 + th, w0 = wq * 7 + tw;
            int ld = (d0 < 14) ? 0 : ((d0 < 15) ? 1 : 2);
            int lh = (h0 < 49) ? 0 : ((h0 < 53) ? 1 : 2);
            int lw = (w0 < 49) ? 0 : ((w0 < 53) ? 1 : 2);
            lv = (unsigned char)((ld * 3 + lh) * 3 + lw);
        }
        labL[t] = lv;
    }
    // zero xw tail rows 98..127 and VTs tail cols 98..139
    for (int e = tid; e < 3000; e += 256) xw[9800 + e] = (_Float16)0.f;
    for (int e = tid; e < 1344; e += 256) {
        int rr = e / 42, cc = 98 + (e - rr * 42);
        VTs[rr * 140 + cc] = (_Float16)0.f;
    }
    // LN1 + cyclic shift gather -> xw
    {
        const int lane = tid & 31, sub = tid >> 5;
        for (int it = 0; it < 13; ++it) {
            int t = sub + 8 * it;
            if (t < 98) {
                int td = t / 49; int r = t - td * 49; int th = r / 7; int tw = r - th * 7;
                int gd = (dq * 2 + td + 1) & 15;
                int gh = hq * 7 + th + 3; if (gh >= 56) gh -= 56;
                int gw = wq * 7 + tw + 3; if (gw >= 56) gw -= 56;
                const float* row = x + (size_t)(((b * 16 + gd) * 56 + gh) * 56 + gw) * 96;
                float v0 = row[lane], v1 = row[lane + 32], v2 = row[lane + 64];
                float s = v0 + v1 + v2, s2 = v0 * v0 + v1 * v1 + v2 * v2;
                #pragma unroll
                for (int off = 16; off >= 1; off >>= 1) {
                    s  += __shfl_xor(s,  off, 32);
                    s2 += __shfl_xor(s2, off, 32);
                }
                float mu = s * (1.f / 96.f);
                float rs = rsqrtf(s2 * (1.f / 96.f) - mu * mu + 1e-5f);
                xw[t * 100 + lane]      = (_Float16)((v0 - mu) * rs * g1v[lane]      + b1v[lane]);
                xw[t * 100 + lane + 32] = (_Float16)((v1 - mu) * rs * g1v[lane + 32] + b1v[lane + 32]);
                xw[t * 100 + lane + 64] = (_Float16)((v2 - mu) * rs * g1v[lane + 64] + b1v[lane + 64]);
            }
        }
    }
    __syncthreads();

    const int l = tid & 63, wid = tid >> 6, n = l & 31, hi = l >> 5;
    const int mtb = wid * 32;          // this wave's token/query tile base

    f16x4 ofr[3][4];                   // per-head O^T B-fragments (k = h*32+hd)

    #pragma unroll
    for (int h = 0; h < 3; ++h) {
        // A-fragments of xw (rows mtb..mtb+31) — reloaded per head to cut live range
        f16x4 af[12];
        #pragma unroll
        for (int ks = 0; ks < 12; ++ks)
            af[ks] = *(const f16x4*)&xw[(mtb + n) * 100 + 8 * ks + 4 * hi];
        // ---- QKV (D[m=t][n=hd]) ----
        #pragma unroll
        for (int sel = 0; sel < 3; ++sel) {
            int ct = sel * 3 + h;
            float bias = b_qkv[sel * 96 + h * 32 + n];
            f32x16 acc;
            #pragma unroll
            for (int r2 = 0; r2 < 16; ++r2) acc[r2] = bias;
            #pragma unroll
            for (int ks = 0; ks < 12; ++ks) {
                f16x4 bf = *(const f16x4*)&wqkvp[((ct * 12 + ks) * 64 + l) * 4];
                acc = __builtin_amdgcn_mfma_f32_32x32x8f16(af[ks], bf, acc, 0, 0, 0);
            }
            #pragma unroll
            for (int rg = 0; rg < 16; ++rg) {
                int t = mtb + (rg & 3) + 8 * (rg >> 2) + 4 * hi;
                float v = acc[rg];
                if (sel == 0)      Qs[t * 36 + n] = (_Float16)(v * SCALE_Q);
                else if (sel == 1) Ks[t * 36 + n] = (_Float16)v;
                else if (t < 98)   VTs[n * 140 + t] = (_Float16)v;
            }
        }
        __syncthreads();

        // ---- S^T = K @ Q^T  (D[m=j][n=i], lane owns query i = mtb+n) ----
        f32x16 sc[4];
        #pragma unroll
        for (int jt = 0; jt < 4; ++jt) {
            f32x16 a;
            #pragma unroll
            for (int r2 = 0; r2 < 16; ++r2) a[r2] = 0.f;
            #pragma unroll
            for (int ks = 0; ks < 4; ++ks) {
                f16x4 ak = *(const f16x4*)&Ks[(jt * 32 + n) * 36 + 8 * ks + 4 * hi];
                f16x4 bq = *(const f16x4*)&Qs[(mtb + n) * 36 + 8 * ks + 4 * hi];
                a = __builtin_amdgcn_mfma_f32_32x32x8f16(ak, bq, a, 0, 0, 0);
            }
            sc[jt] = a;
        }
        // bias + mask + in-lane softmax
        {
            const int i = mtb + n;
            const bool iv = (i < 98);
            const unsigned char li = labL[i];
            const float* bb = biasbT + (size_t)h * 9604;
            float m = -1e30f;
            #pragma unroll
            for (int jt = 0; jt < 4; ++jt) {
                #pragma unroll
                for (int rg = 0; rg < 16; ++rg) {
                    int j = jt * 32 + (rg & 3) + 8 * (rg >> 2) + 4 * hi;
                    float s;
                    if (j < 98 && iv)
                        s = sc[jt][rg] + bb[j * 98 + i] + ((li != labL[j]) ? -100.f : 0.f);
                    else
                        s = -1e30f;
                    sc[jt][rg] = s;
                    m = fmaxf(m, s);
                }
            }
            m = fmaxf(m, __shfl_xor(m, 32));
            float ssum = 0.f;
            #pragma unroll
            for (int jt = 0; jt < 4; ++jt)
                #pragma unroll
                for (int rg = 0; rg < 16; ++rg) {
                    float p = __expf(sc[jt][rg] - m);
                    sc[jt][rg] = p;
                    ssum += p;
                }
            ssum += __shfl_xor(ssum, 32);
            float inv = 1.f / ssum;
            #pragma unroll
            for (int jt = 0; jt < 4; ++jt)
                #pragma unroll
                for (int rg = 0; rg < 16; ++rg) sc[jt][rg] *= inv;
        }
        // ---- PV: O^T[hd][t] ; B = P^T straight from sc registers ----
        {
            f32x16 oacc;
            #pragma unroll
            for (int r2 = 0; r2 < 16; ++r2) oacc[r2] = 0.f;
            #pragma unroll
            for (int jt = 0; jt < 4; ++jt) {
                #pragma unroll
                for (int s4 = 0; s4 < 4; ++s4) {
                    f16x4 pf;
                    pf[0] = (_Float16)sc[jt][4 * s4 + 0];
                    pf[1] = (_Float16)sc[jt][4 * s4 + 1];
                    pf[2] = (_Float16)sc[jt][4 * s4 + 2];
                    pf[3] = (_Float16)sc[jt][4 * s4 + 3];
                    f16x4 av = *(const f16x4*)&VTs[n * 140 + 8 * (jt * 4 + s4) + 4 * hi];
                    oacc = __builtin_amdgcn_mfma_f32_32x32x8f16(av, pf, oacc, 0, 0, 0);
                }
            }
            #pragma unroll
            for (int s4 = 0; s4 < 4; ++s4) {
                f16x4 q;
                q[0] = (_Float16)oacc[4 * s4 + 0];
                q[1] = (_Float16)oacc[4 * s4 + 1];
                q[2] = (_Float16)oacc[4 * s4 + 2];
                q[3] = (_Float16)oacc[4 * s4 + 3];
                ofr[h][s4] = q;
            }
        }
        __syncthreads();   // before next head's QKV overwrites Qs/Ks/VTs (also guards stage alias)
    }

    // ---- proj: OUT^T[col][t] ; B = O^T from registers, A = packed Wp^T ----
    #pragma unroll
    for (int ct = 0; ct < 3; ++ct) {
        f32x16 acc;
        #pragma unroll
        for (int r2 = 0; r2 < 16; ++r2) acc[r2] = 0.f;
        #pragma unroll
        for (int S = 0; S < 12; ++S) {
            f16x4 aw = *(const f16x4*)&wpp[((ct * 12 + S) * 64 + l) * 4];
            acc = __builtin_amdgcn_mfma_f32_32x32x8f16(aw, ofr[S >> 2][S & 3], acc, 0, 0, 0);
        }
        int t = mtb + n;
        if (t < 98) {
            #pragma unroll
            for (int rg = 0; rg < 16; ++rg) {
                int col = ct * 32 + (rg & 3) + 8 * (rg >> 2) + 4 * hi;
                stage[t * 97 + col] = acc[rg];
            }
        }
    }
    __syncthreads();
    // ---- out = x + stage + b_proj (coalesced float4) ----
    for (int e = tid; e < 2352; e += 256) {
        int t = e / 24, q4 = (e - (e / 24) * 24) * 4;
        int td = t / 49; int r = t - td * 49; int th = r / 7; int tw = r - th * 7;
        int gd = (dq * 2 + td + 1) & 15;
        int gh = hq * 7 + th + 3; if (gh >= 56) gh -= 56;
        int gw = wq * 7 + tw + 3; if (gw >= 56) gw -= 56;
        size_t base = (size_t)(((b * 16 + gd) * 56 + gh) * 56 + gw) * 96 + q4;
        float4 xv = *(const float4*)&x[base];
        float4 bp = *(const float4*)&b_proj[q4];
        float4 ov;
        ov.x = xv.x + bp.x + stage[t * 97 + q4 + 0];
        ov.y = xv.y + bp.y + stage[t * 97 + q4 + 1];
        ov.z = xv.z + bp.z + stage[t * 97 + q4 + 2];
        ov.w = xv.w + bp.w + stage[t * 97 + q4 + 3];
        *(float4*)&out[base] = ov;
    }
}

// ---------------- MLP: LN2 + FC1 + GELU + FC2 + residual, 64 tokens/block ----------------
__global__ __launch_bounds__(256, 2) void k_mlp4(
    const float* __restrict__ g2v, const float* __restrict__ b2v,
    const float* __restrict__ b_fc1, const float* __restrict__ b_fc2,
    const char* __restrict__ ws,
    float* __restrict__ out) {
    __shared__ _Float16 xb[64 * 100];
    __shared__ _Float16 hb[64 * 388];
    const _Float16* w1p = (const _Float16*)(ws + W1P_OFF);
    const _Float16* w2p = (const _Float16*)(ws + W2P_OFF);
    const int tid = threadIdx.x;
    const size_t tokBase = (size_t)blockIdx.x * 64;
    {
        const int lane = tid & 31, sub = tid >> 5;
        for (int it = 0; it < 8; ++it) {
            int rt = sub + 8 * it;
            const float* row = out + (tokBase + rt) * 96;
            float v0 = row[lane], v1 = row[lane + 32], v2 = row[lane + 64];
            float s = v0 + v1 + v2, s2 = v0 * v0 + v1 * v1 + v2 * v2;
            #pragma unroll
            for (int off = 16; off >= 1; off >>= 1) {
                s  += __shfl_xor(s,  off, 32);
                s2 += __shfl_xor(s2, off, 32);
            }
            float mu = s * (1.f / 96.f);
            float rs = rsqrtf(s2 * (1.f / 96.f) - mu * mu + 1e-5f);
            xb[rt * 100 + lane]      = (_Float16)((v0 - mu) * rs * g2v[lane]      + b2v[lane]);
            xb[rt * 100 + lane + 32] = (_Float16)((v1 - mu) * rs * g2v[lane + 32] + b2v[lane + 32]);
            xb[rt * 100 + lane + 64] = (_Float16)((v2 - mu) * rs * g2v[lane + 64] + b2v[lane + 64]);
        }
    }
    __syncthreads();
    const int l = tid & 63, wid = tid >> 6, n = l & 31, hi = l >> 5;
    // FC1 + GELU -> hb
    {
        const int mt = wid & 1;
        const int nt0 = wid >> 1;
        f16x4 af[12];
        #pragma unroll
        for (int ks = 0; ks < 12; ++ks)
            af[ks] = *(const f16x4*)&xb[(mt * 32 + n) * 100 + 8 * ks + 4 * hi];
        for (int s6 = 0; s6 < 6; ++s6) {
            int nt = nt0 + 2 * s6;
            float bias = b_fc1[nt * 32 + n];
            f32x16 acc;
            #pragma unroll
            for (int r2 = 0; r2 < 16; ++r2) acc[r2] = bias;
            #pragma unroll
            for (int ks = 0; ks < 12; ++ks) {
                f16x4 bf = *(const f16x4*)&w1p[((nt * 12 + ks) * 64 + l) * 4];
                acc = __builtin_amdgcn_mfma_f32_32x32x8f16(af[ks], bf, acc, 0, 0, 0);
            }
            #pragma unroll
            for (int rg = 0; rg < 16; ++rg) {
                int r2 = mt * 32 + (rg & 3) + 8 * (rg >> 2) + 4 * hi;
                float v = acc[rg];
                hb[r2 * 388 + nt * 32 + n] = (_Float16)(0.5f * v * (1.f + erff(v * 0.70710678118654752f)));
            }
        }
    }
    __syncthreads();
    // FC2 + residual
    for (int u = wid; u < 6; u += 4) {
        int nt = u >> 1, mt = u & 1;
        float bias = b_fc2[nt * 32 + n];
        f32x16 acc;
        #pragma unroll
        for (int r2 = 0; r2 < 16; ++r2) acc[r2] = bias;
        #pragma unroll
        for (int ks = 0; ks < 48; ++ks) {
            f16x4 ah = *(const f16x4*)&hb[(mt * 32 + n) * 388 + 8 * ks + 4 * hi];
            f16x4 bf = *(const f16x4*)&w2p[((nt * 48 + ks) * 64 + l) * 4];
            acc = __builtin_amdgcn_mfma_f32_32x32x8f16(ah, bf, acc, 0, 0, 0);
        }
        #pragma unroll
        for (int rg = 0; rg < 16; ++rg) {
            int t = mt * 32 + (rg & 3) + 8 * (rg >> 2) + 4 * hi;
            size_t idx = (tokBase + t) * 96 + nt * 32 + n;
            out[idx] = out[idx] + acc[rg];
        }
    }
}

extern "C" void kernel_launch(void* const* d_in, const int* in_sizes, int n_in,
                              void* d_out, int out_size, void* d_ws, size_t ws_size,
                              hipStream_t stream) {
    const float* x      = (const float*)d_in[0];
    const float* g1     = (const float*)d_in[2];
    const float* b1     = (const float*)d_in[3];
    const float* w_qkv  = (const float*)d_in[4];
    const float* b_qkv  = (const float*)d_in[5];
    const float* w_proj = (const float*)d_in[6];
    const float* b_proj = (const float*)d_in[7];
    const float* btab   = (const float*)d_in[8];
    const int*   relidx = (const int*)d_in[9];
    const float* g2     = (const float*)d_in[10];
    const float* b2     = (const float*)d_in[11];
    const float* w_fc1  = (const float*)d_in[12];
    const float* b_fc1  = (const float*)d_in[13];
    const float* w_fc2  = (const float*)d_in[14];
    const float* b_fc2  = (const float*)d_in[15];
    float* out = (float*)d_out;
    char*  ws  = (char*)d_ws;

    hipLaunchKernelGGL(k_prep, dim3(545), dim3(256), 0, stream,
                       w_qkv, w_proj, w_fc1, w_fc2, btab, relidx, ws);
    hipLaunchKernelGGL(k_attn5, dim3(4096), dim3(256), 0, stream,
                       x, g1, b1, b_qkv, b_proj, (const char*)ws, out);
    hipLaunchKernelGGL(k_mlp4, dim3(401408 / 64), dim3(256), 0, stream,
                       g2, b2, b_fc1, b_fc2, (const char*)ws, out);
}